// Round 6
// baseline (380.180 us; speedup 1.0000x reference)
//
#include <hip/hip_runtime.h>
#include <hip/hip_bf16.h>

using bf16 = __hip_bfloat16;
using s8v  = __attribute__((ext_vector_type(8))) short;
using f4v  = __attribute__((ext_vector_type(4))) float;

constexpr int B_   = 4;
constexpr int P_   = 1024;
constexpr int KNB  = 32;
constexpr int D_   = 768;
constexpr int H_   = 12;
constexpr int S_   = P_ + 1;    // 1025
constexpr int M_   = B_ * S_;   // 4100
constexpr int MPAD = 4224;      // 66 * 64

#define DEVI static __device__ __forceinline__
#define WAITVM(N) asm volatile("s_waitcnt vmcnt(" #N ")" ::: "memory")
#define MEMFENCE  asm volatile("" ::: "memory")

DEVI float b2f_lo(unsigned u) { return __builtin_bit_cast(float, u << 16); }
DEVI float b2f_hi(unsigned u) { return __builtin_bit_cast(float, u & 0xffff0000u); }
DEVI unsigned short f2bu(float f) {
  return __builtin_bit_cast(unsigned short, __float2bfloat16(f));
}

// ---------------- prep: 4x weight transpose-convert + LN1, one dispatch ----------------
DEVI void wt_conv_dev(const float* __restrict__ W, bf16* __restrict__ Wt,
                      int KK, int NN, int idx, int tid, float (*t)[33]) {
  int nbn = NN >> 5;
  int bk = (idx / nbn) * 32, bn = (idx % nbn) * 32;
  int tx = tid & 31, ty = tid >> 5;  // ty in 0..7
#pragma unroll
  for (int i = 0; i < 32; i += 8)
    t[ty + i][tx] = W[(size_t)(bk + ty + i) * NN + bn + tx];
  __syncthreads();
#pragma unroll
  for (int i = 0; i < 32; i += 8)
    Wt[(size_t)(bn + ty + i) * KK + bk + tx] = __float2bfloat16(t[tx][ty + i]);
}

DEVI void ln_dev(const float* __restrict__ xr, const float* __restrict__ w,
                 const float* __restrict__ b, bf16* __restrict__ orow,
                 int t, float* sm, float* sv) {
  float v0 = xr[t], v1 = xr[t + 256], v2 = xr[t + 512];
  float s = v0 + v1 + v2;
  float ss = v0 * v0 + v1 * v1 + v2 * v2;
#pragma unroll
  for (int o = 32; o; o >>= 1) { s += __shfl_xor(s, o); ss += __shfl_xor(ss, o); }
  if ((t & 63) == 0) { sm[t >> 6] = s; sv[t >> 6] = ss; }
  __syncthreads();
  float S = sm[0] + sm[1] + sm[2] + sm[3];
  float SS = sv[0] + sv[1] + sv[2] + sv[3];
  float mean = S * (1.f / D_);
  float var  = SS * (1.f / D_) - mean * mean;
  float inv  = rsqrtf(var + 1e-5f);
  orow[t]       = __float2bfloat16((v0 - mean) * inv * w[t]       + b[t]);
  orow[t + 256] = __float2bfloat16((v1 - mean) * inv * w[t + 256] + b[t + 256]);
  orow[t + 512] = __float2bfloat16((v2 - mean) * inv * w[t + 512] + b[t + 512]);
}

__global__ __launch_bounds__(256)
void prep(const float* __restrict__ qkv_w, const float* __restrict__ proj_w,
          const float* __restrict__ mlp_w1, const float* __restrict__ mlp_w2,
          bf16* qkvw_t, bf16* projw_t, bf16* mlpw1_t, bf16* mlpw2_t,
          const float* __restrict__ x, const float* __restrict__ ln1_w,
          const float* __restrict__ ln1_b, bf16* xnA) {
  __shared__ float t[32][33];
  __shared__ float sm[4], sv[4];
  int idx = blockIdx.x, tid = threadIdx.x;
  if (idx < 1728)       wt_conv_dev(qkv_w,  qkvw_t,  768,  2304, idx,        tid, t);
  else if (idx < 2304)  wt_conv_dev(proj_w, projw_t, 768,  768,  idx - 1728, tid, t);
  else if (idx < 4608)  wt_conv_dev(mlp_w1, mlpw1_t, 768,  3072, idx - 2304, tid, t);
  else if (idx < 6912)  wt_conv_dev(mlp_w2, mlpw2_t, 3072, 768,  idx - 4608, tid, t);
  else {
    int row = idx - 6912;  // 0..M_-1
    ln_dev(x + (size_t)row * D_, ln1_w, ln1_b, xnA + (size_t)row * D_, tid, sm, sv);
  }
}

// ---------------- bf16 GEMM, BM=64, depth-3 counted-vmcnt pipeline ----------------
// C = A(rows x KSTRIDE) * Bt(NxKSTRIDE)^T over K-chunk [kbase, kbase+KCHUNK).
// grid.x = 66*(N/128) swizzled blocks; grid.y = K-chunk index (split-K).
// MODE 0: + bias -> scatter to QKV buffer [3][B][S][768] bf16
// MODE 2: + bias -> gelu(exact) -> bf16 dst [M_][N]  (rows < M_ only)
// MODE 3: bf16 partial -> dst + blockIdx.y*MPAD*N (no bias)
template<int N, int KSTRIDE, int KCHUNK, int MODE>
__global__ __launch_bounds__(256)
void gemm_bf16(const bf16* __restrict__ A, const bf16* __restrict__ Bt,
               const float* __restrict__ bias, void* __restrict__ dst) {
  constexpr int BM   = 64;
  constexpr int MR   = 2;              // m-fragments per wave (wave rows = 32)
  constexpr int TN   = N / 128;
  constexpr int NBLK = (MPAD / BM) * TN;
  __shared__ bf16 ldsA[3][BM * 32];
  __shared__ bf16 ldsB[3][128 * 32];

  // bijective XCD-chunked remap (m204): XCD k gets a contiguous tm-major chunk
  int bid = blockIdx.x;
  constexpr int NQ = NBLK >> 3, NR = NBLK & 7;
  int xcd = bid & 7, off = bid >> 3;
  int swz = (xcd < NR ? xcd * (NQ + 1) : NR * (NQ + 1) + (xcd - NR) * NQ) + off;
  const int tm = swz / TN, tn = swz % TN;
  const int kbase = blockIdx.y * KCHUNK;

  const int tid = threadIdx.x;
  const int wid = tid >> 6, lane = tid & 63;
  const int wr = wid >> 1, wc = wid & 1;

  auto stage = [&](int bufi, int step) {
    const int k0 = kbase + step * 32;
    {
      int c = wid * 64 + lane;           // 0..255 -> 64 rows x 4 slots
      int r = c >> 2, slot = c & 3;
      int gs = slot ^ ((r >> 1) & 3);    // inverse-swizzled global source (rule 21)
      const bf16* ga = A + (size_t)(tm * BM + r) * KSTRIDE + k0 + gs * 8;
      bf16* la = &ldsA[bufi][(wid * 64 + lane) * 8];
      __builtin_amdgcn_global_load_lds(
          (__attribute__((address_space(1))) void*)ga,
          (__attribute__((address_space(3))) void*)la, 16, 0, 0);
    }
#pragma unroll
    for (int i = 0; i < 2; ++i) {
      int c = wid * 64 + i * 256 + lane;
      int r = c >> 2, slot = c & 3;
      int gs = slot ^ ((r >> 1) & 3);
      const bf16* ga = Bt + (size_t)(tn * 128 + r) * KSTRIDE + k0 + gs * 8;
      bf16* la = &ldsB[bufi][(wid * 64 + i * 256) * 8];
      __builtin_amdgcn_global_load_lds(
          (__attribute__((address_space(1))) void*)ga,
          (__attribute__((address_space(3))) void*)la, 16, 0, 0);
    }
  };

  f4v acc[MR][4] = {};
  const int nk = KCHUNK / 32;

  stage(0, 0); stage(1, 1);   // 2 stages (6 loads) in flight

#pragma unroll 3
  for (int kt = 0; kt < nk; ++kt) {
    if (kt < nk - 1) WAITVM(3);   // oldest stage done; 1 stage still in flight
    else             WAITVM(0);
    __builtin_amdgcn_s_barrier();   // stage(kt) visible; buf[(kt+2)%3] free (WAR ok)
    MEMFENCE;
    if (kt + 2 < nk) stage((kt + 2) % 3, kt + 2);  // 2-iteration runway

    const int cur = kt % 3;
    s8v af[MR], bfv[4];
#pragma unroll
    for (int m = 0; m < MR; ++m) {
      int row = wr * 32 + m * 16 + (lane & 15);
      int slot = (lane >> 4) ^ ((row >> 1) & 3);
      af[m] = *(const s8v*)&ldsA[cur][row * 32 + slot * 8];
    }
#pragma unroll
    for (int n = 0; n < 4; ++n) {
      int row = wc * 64 + n * 16 + (lane & 15);
      int slot = (lane >> 4) ^ ((row >> 1) & 3);
      bfv[n] = *(const s8v*)&ldsB[cur][row * 32 + slot * 8];
    }
#pragma unroll
    for (int m = 0; m < MR; ++m)
#pragma unroll
      for (int n = 0; n < 4; ++n)
        acc[m][n] = __builtin_amdgcn_mfma_f32_16x16x32_bf16(af[m], bfv[n], acc[m][n], 0, 0, 0);
  }

#pragma unroll
  for (int m = 0; m < MR; ++m)
#pragma unroll
    for (int n = 0; n < 4; ++n)
#pragma unroll
      for (int j = 0; j < 4; ++j) {
        int row = tm * 64 + wr * 32 + m * 16 + (lane >> 4) * 4 + j;
        int col = tn * 128 + wc * 64 + n * 16 + (lane & 15);   // C: col=l&15 (m89)
        float v = acc[m][n][j];
        if (MODE == 0) {
          if (row < M_) {
            float val = v + bias[col];
            int which = col / 768, rem2 = col % 768;
            int bb = row / S_, s = row % S_;
            ((bf16*)dst)[((size_t)(which * B_ + bb) * S_ + s) * 768 + rem2] =
                __float2bfloat16(val);
          }
        } else if (MODE == 2) {
          if (row < M_) {
            float val = v + bias[col];
            val = 0.5f * val * (1.f + erff(val * 0.70710678f));
            ((bf16*)dst)[(size_t)row * N + col] = __float2bfloat16(val);
          }
        } else {
          bf16* p = (bf16*)dst + (size_t)blockIdx.y * MPAD * N;
          p[(size_t)row * N + col] = __float2bfloat16(v);
        }
      }
}

// ---------------- proj reduce + residual + LN2, fused (one row per block) ----------------
__global__ __launch_bounds__(256)
void projfix(const bf16* __restrict__ part, const float* __restrict__ x,
             const float* __restrict__ pbias, const float* __restrict__ lnw,
             const float* __restrict__ lnb, float* __restrict__ out,
             bf16* __restrict__ h2) {
  int row = blockIdx.x, t = threadIdx.x;
  const bf16* p0 = part + (size_t)row * D_;
  const bf16* p1 = part + (size_t)MPAD * D_ + (size_t)row * D_;
  const float* xr = x + (size_t)row * D_;
  float v[3];
#pragma unroll
  for (int i = 0; i < 3; ++i) {
    int c = t + i * 256;
    v[i] = xr[c] + pbias[c] + __bfloat162float(p0[c]) + __bfloat162float(p1[c]);
  }
  float* orow = out + (size_t)row * D_;
#pragma unroll
  for (int i = 0; i < 3; ++i) orow[t + i * 256] = v[i];
  float s = v[0] + v[1] + v[2];
  float ss = v[0] * v[0] + v[1] * v[1] + v[2] * v[2];
#pragma unroll
  for (int o = 32; o; o >>= 1) { s += __shfl_xor(s, o); ss += __shfl_xor(ss, o); }
  __shared__ float sm[4], sv[4];
  if ((t & 63) == 0) { sm[t >> 6] = s; sv[t >> 6] = ss; }
  __syncthreads();
  float S = sm[0] + sm[1] + sm[2] + sm[3];
  float SS = sv[0] + sv[1] + sv[2] + sv[3];
  float mean = S * (1.f / D_);
  float var  = SS * (1.f / D_) - mean * mean;
  float inv  = rsqrtf(var + 1e-5f);
  bf16* hrow = h2 + (size_t)row * D_;
#pragma unroll
  for (int i = 0; i < 3; ++i) {
    int c = t + i * 256;
    hrow[c] = __float2bfloat16((v[i] - mean) * inv * lnw[c] + lnb[c]);
  }
}

// ---------------- mlp2 split-K reduce (in-place residual) ----------------
__global__ __launch_bounds__(256)
void reduceK(const bf16* __restrict__ part, const float* __restrict__ bias,
             float* __restrict__ out) {
  int i = blockIdx.x * 256 + threadIdx.x;   // float4 units; M_*768/4 total
  ushort4 a = ((const ushort4*)part)[i];
  ushort4 b = ((const ushort4*)(part + (size_t)MPAD * 768))[i];
  float4 s = ((const float4*)out)[i];
  int col = (i * 4) % D_;
  float4 bv = *(const float4*)&bias[col];
  float4 o;
  o.x = s.x + bv.x + b2f_lo((unsigned)a.x << 16 >> 16 << 16 >> 16 | 0) ; // placeholder avoided
  // (simple scalar converts below)
  o.x = s.x + bv.x + __bfloat162float(__hip_bfloat16_raw{a.x}) + __bfloat162float(__hip_bfloat16_raw{b.x});
  o.y = s.y + bv.y + __bfloat162float(__hip_bfloat16_raw{a.y}) + __bfloat162float(__hip_bfloat16_raw{b.y});
  o.z = s.z + bv.z + __bfloat162float(__hip_bfloat16_raw{a.z}) + __bfloat162float(__hip_bfloat16_raw{b.z});
  o.w = s.w + bv.w + __bfloat162float(__hip_bfloat16_raw{a.w}) + __bfloat162float(__hip_bfloat16_raw{b.w});
  ((float4*)out)[i] = o;
}

// ---------------- attention: routed (blocks 0..12287) + cls (blocks 12288..12335) ----------------
__global__ __launch_bounds__(256)
void attn_kernel(const bf16* __restrict__ QKV, const int* __restrict__ routes,
                 bf16* __restrict__ out) {
  __shared__ float qf[64];
  __shared__ float sc[S_];
  __shared__ float red[4];
  __shared__ float pv[4][64];

  if (blockIdx.x < 12288) {
    // ---- routed: one wave per (b,p,h), no barriers ----
    int unit = blockIdx.x * 4 + (threadIdx.x >> 6);  // (b*P + p)*H + h
    int lane = threadIdx.x & 63;
    int h = unit % H_;
    int bp = unit / H_;
    int p = bp % P_, b = bp / P_;

    int k = lane & 31, hi = lane >> 5;
    int r = routes[p * KNB + k] + 1;

    const bf16* Qp = QKV + ((size_t)(0 * B_ + b) * S_ + (p + 1)) * D_ + h * 64 + hi * 32;
    const bf16* Kb = QKV + ((size_t)(1 * B_ + b) * S_) * D_;
    const bf16* Vb = QKV + ((size_t)(2 * B_ + b) * S_) * D_;

    const uint4* q4 = (const uint4*)Qp;
    const uint4* k4 = (const uint4*)(Kb + (size_t)r * D_ + h * 64 + hi * 32);
    float dot = 0.f;
#pragma unroll
    for (int i = 0; i < 4; ++i) {
      uint4 qv = q4[i], kv = k4[i];
      dot += b2f_lo(kv.x) * b2f_lo(qv.x) + b2f_hi(kv.x) * b2f_hi(qv.x)
           + b2f_lo(kv.y) * b2f_lo(qv.y) + b2f_hi(kv.y) * b2f_hi(qv.y)
           + b2f_lo(kv.z) * b2f_lo(qv.z) + b2f_hi(kv.z) * b2f_hi(qv.z)
           + b2f_lo(kv.w) * b2f_lo(qv.w) + b2f_hi(kv.w) * b2f_hi(qv.w);
    }
    dot += __shfl_xor(dot, 32);
    float scv = dot * 0.125f;

    float mx = scv;
#pragma unroll
    for (int o = 16; o; o >>= 1) mx = fmaxf(mx, __shfl_xor(mx, o));
    float w = __expf(scv - mx);
    float sum = w;
#pragma unroll
    for (int o = 16; o; o >>= 1) sum += __shfl_xor(sum, o);
    float inv = 1.f / sum;

    int c = lane & 7, kr0 = lane >> 3;
    float acc[8] = {};
#pragma unroll
    for (int j = 0; j < 4; ++j) {
      int kj = (kr0 & 7) + 8 * j;
      float wj = __shfl(w, kj);
      int rj = __shfl(r, kj);
      uint4 vv = *(const uint4*)(Vb + (size_t)rj * D_ + h * 64 + c * 8);
      acc[0] += wj * b2f_lo(vv.x); acc[1] += wj * b2f_hi(vv.x);
      acc[2] += wj * b2f_lo(vv.y); acc[3] += wj * b2f_hi(vv.y);
      acc[4] += wj * b2f_lo(vv.z); acc[5] += wj * b2f_hi(vv.z);
      acc[6] += wj * b2f_lo(vv.w); acc[7] += wj * b2f_hi(vv.w);
    }
#pragma unroll
    for (int s = 8; s < 64; s <<= 1)
#pragma unroll
      for (int d = 0; d < 8; ++d) acc[d] += __shfl_xor(acc[d], s);

    if (lane < 8) {
      s8v o;
#pragma unroll
      for (int d = 0; d < 8; ++d) o[d] = (short)f2bu(acc[d] * inv);
      *(s8v*)(out + ((size_t)(b * S_ + p + 1)) * D_ + h * 64 + c * 8) = o;
    }
  } else {
    // ---- cls token: one block per (b,h), full-S softmax ----
    int bh = blockIdx.x - 12288;
    int b = bh / H_, h = bh % H_;
    const bf16* q  = QKV + ((size_t)(0 * B_ + b) * S_) * D_ + h * 64;
    const bf16* Kr = QKV + ((size_t)(1 * B_ + b) * S_) * D_ + h * 64;
    const bf16* Vr = QKV + ((size_t)(2 * B_ + b) * S_) * D_ + h * 64;
    int t = threadIdx.x;
    if (t < 64) qf[t] = __bfloat162float(q[t]);
    __syncthreads();
    for (int kk = t; kk < S_; kk += 256) {
      const uint4* k4 = (const uint4*)(Kr + (size_t)kk * D_);
      float s = 0.f;
#pragma unroll
      for (int i = 0; i < 8; ++i) {
        uint4 kv = k4[i];
        const float* q8 = &qf[i * 8];
        s += b2f_lo(kv.x) * q8[0] + b2f_hi(kv.x) * q8[1]
           + b2f_lo(kv.y) * q8[2] + b2f_hi(kv.y) * q8[3]
           + b2f_lo(kv.z) * q8[4] + b2f_hi(kv.z) * q8[5]
           + b2f_lo(kv.w) * q8[6] + b2f_hi(kv.w) * q8[7];
      }
      sc[kk] = s * 0.125f;
    }
    __syncthreads();
    float mx = -1e30f;
    for (int kk = t; kk < S_; kk += 256) mx = fmaxf(mx, sc[kk]);
#pragma unroll
    for (int o = 32; o; o >>= 1) mx = fmaxf(mx, __shfl_xor(mx, o));
    if ((t & 63) == 0) red[t >> 6] = mx;
    __syncthreads();
    float M = fmaxf(fmaxf(red[0], red[1]), fmaxf(red[2], red[3]));
    __syncthreads();
    float sum = 0.f;
    for (int kk = t; kk < S_; kk += 256) { float e = __expf(sc[kk] - M); sc[kk] = e; sum += e; }
#pragma unroll
    for (int o = 32; o; o >>= 1) sum += __shfl_xor(sum, o);
    if ((t & 63) == 0) red[t >> 6] = sum;
    __syncthreads();
    float L = red[0] + red[1] + red[2] + red[3];
    float inv = 1.f / L;
    int d = t & 63, kg = t >> 6;
    float acc = 0.f;
    for (int kk = kg; kk < S_; kk += 4)
      acc += sc[kk] * __bfloat162float(Vr[(size_t)kk * D_ + d]);
    pv[kg][d] = acc;
    __syncthreads();
    if (t < 64) {
      float ov = (pv[0][t] + pv[1][t] + pv[2][t] + pv[3][t]) * inv;
      out[(size_t)(b * S_) * D_ + h * 64 + t] = __float2bfloat16(ov);
    }
  }
}

extern "C" void kernel_launch(void* const* d_in, const int* in_sizes, int n_in,
                              void* d_out, int out_size, void* d_ws, size_t ws_size,
                              hipStream_t stream) {
  const float* x      = (const float*)d_in[0];
  const int*   routes = (const int*)d_in[1];
  const float* qkv_w  = (const float*)d_in[2];
  const float* qkv_b  = (const float*)d_in[3];
  const float* proj_w = (const float*)d_in[4];
  const float* proj_b = (const float*)d_in[5];
  const float* ln1_w  = (const float*)d_in[6];
  const float* ln1_b  = (const float*)d_in[7];
  const float* ln2_w  = (const float*)d_in[8];
  const float* ln2_b  = (const float*)d_in[9];
  const float* mlp_w1 = (const float*)d_in[10];
  const float* mlp_b1 = (const float*)d_in[11];
  const float* mlp_w2 = (const float*)d_in[12];
  const float* mlp_b2 = (const float*)d_in[13];
  float* out = (float*)d_out;

  // workspace layout (~52.5 MB, same footprint as proven rounds)
  bf16* qkvw_t  = (bf16*)d_ws;                       // [2304][768]
  bf16* projw_t = qkvw_t + 2304 * 768;               // [768][768]
  bf16* mlpw1_t = projw_t + 768 * 768;               // [3072][768]
  bf16* mlpw2_t = mlpw1_t + 3072 * 768;              // [768][3072]
  bf16* xnA     = mlpw2_t + 768 * 3072;              // [4224][768]
  bf16* qkvbuf  = xnA + (size_t)MPAD * 768;          // [3][B][S][768] s-major
  bf16* attn    = qkvbuf + (size_t)3 * B_ * S_ * 768;  // [4224][768]
  bf16* h2      = attn + (size_t)MPAD * 768;         // [4224][768]
  // aliases (lifetime-checked):
  bf16* g       = xnA;   // [M_][3072]: reads up to MPAD rows stay inside ws (garbage pads ok)
  bf16* projp   = xnA;   // proj partials [2][MPAD][768] over xnA+qkvbuf-head (dead after attn)
  bf16* mlp2p   = attn;  // mlp2 partials [2][MPAD][768] over attn+h2 (both dead by then)

  // 1. prep: all 4 weight converts + LN1 (mutually independent)
  prep<<<6912 + M_, 256, 0, stream>>>(qkv_w, proj_w, mlp_w1, mlp_w2,
                                      qkvw_t, projw_t, mlpw1_t, mlpw2_t,
                                      x, ln1_w, ln1_b, xnA);

  // 2. qkv GEMM -> scatter [3][B][S][768]
  gemm_bf16<2304, 768, 768, 0><<<66 * 18, 256, 0, stream>>>(xnA, qkvw_t, qkv_b, qkvbuf);

  // 3. attention (routed + cls merged)
  attn_kernel<<<12288 + B_ * H_, 256, 0, stream>>>(qkvbuf, routes, attn);

  // 4. proj split-K x2 partials
  gemm_bf16<768, 768, 384, 3><<<dim3(66 * 6, 2), 256, 0, stream>>>(attn, projw_t, nullptr, projp);

  // 5. fused: out = x + proj_b + p0 + p1 ; h2 = LN2(out)
  projfix<<<M_, 256, 0, stream>>>(projp, x, proj_b, ln2_w, ln2_b, out, h2);

  // 6. mlp1 + GELU
  gemm_bf16<3072, 768, 768, 2><<<66 * 24, 256, 0, stream>>>(h2, mlpw1_t, mlp_b1, g);

  // 7. mlp2 split-K x2 partials
  gemm_bf16<768, 3072, 1536, 3><<<dim3(66 * 6, 2), 256, 0, stream>>>(g, mlpw2_t, nullptr, mlp2p);

  // 8. final reduce: out += mlp_b2 + p0 + p1
  reduceK<<<(M_ * D_) / 1024, 256, 0, stream>>>(mlp2p, mlp_b2, out);
}

// Round 7
// 378.493 us; speedup vs baseline: 1.0045x; 1.0045x over previous
//
#include <hip/hip_runtime.h>
#include <hip/hip_bf16.h>

using bf16 = __hip_bfloat16;
using s8v  = __attribute__((ext_vector_type(8))) short;
using f4v  = __attribute__((ext_vector_type(4))) float;

constexpr int B_   = 4;
constexpr int P_   = 1024;
constexpr int KNB  = 32;
constexpr int D_   = 768;
constexpr int H_   = 12;
constexpr int S_   = P_ + 1;    // 1025
constexpr int M_   = B_ * S_;   // 4100
constexpr int MPAD = 4224;      // 66 * 64 = 33 * 128

#define DEVI static __device__ __forceinline__
#define WAITVM(N) asm volatile("s_waitcnt vmcnt(" #N ")" ::: "memory")
#define MEMFENCE  asm volatile("" ::: "memory")

DEVI float b2f_lo(unsigned u) { return __builtin_bit_cast(float, u << 16); }
DEVI float b2f_hi(unsigned u) { return __builtin_bit_cast(float, u & 0xffff0000u); }
DEVI unsigned short f2bu(float f) {
  return __builtin_bit_cast(unsigned short, __float2bfloat16(f));
}

// ---------------- prep: 4x weight transpose-convert + LN1, one dispatch ----------------
DEVI void wt_conv_dev(const float* __restrict__ W, bf16* __restrict__ Wt,
                      int KK, int NN, int idx, int tid, float (*t)[33]) {
  int nbn = NN >> 5;
  int bk = (idx / nbn) * 32, bn = (idx % nbn) * 32;
  int tx = tid & 31, ty = tid >> 5;  // ty in 0..7
#pragma unroll
  for (int i = 0; i < 32; i += 8)
    t[ty + i][tx] = W[(size_t)(bk + ty + i) * NN + bn + tx];
  __syncthreads();
#pragma unroll
  for (int i = 0; i < 32; i += 8)
    Wt[(size_t)(bn + ty + i) * KK + bk + tx] = __float2bfloat16(t[tx][ty + i]);
}

DEVI void ln_dev(const float* __restrict__ xr, const float* __restrict__ w,
                 const float* __restrict__ b, bf16* __restrict__ orow,
                 int t, float* sm, float* sv) {
  float v0 = xr[t], v1 = xr[t + 256], v2 = xr[t + 512];
  float s = v0 + v1 + v2;
  float ss = v0 * v0 + v1 * v1 + v2 * v2;
#pragma unroll
  for (int o = 32; o; o >>= 1) { s += __shfl_xor(s, o); ss += __shfl_xor(ss, o); }
  if ((t & 63) == 0) { sm[t >> 6] = s; sv[t >> 6] = ss; }
  __syncthreads();
  float S = sm[0] + sm[1] + sm[2] + sm[3];
  float SS = sv[0] + sv[1] + sv[2] + sv[3];
  float mean = S * (1.f / D_);
  float var  = SS * (1.f / D_) - mean * mean;
  float inv  = rsqrtf(var + 1e-5f);
  orow[t]       = __float2bfloat16((v0 - mean) * inv * w[t]       + b[t]);
  orow[t + 256] = __float2bfloat16((v1 - mean) * inv * w[t + 256] + b[t + 256]);
  orow[t + 512] = __float2bfloat16((v2 - mean) * inv * w[t + 512] + b[t + 512]);
}

__global__ __launch_bounds__(256)
void prep(const float* __restrict__ qkv_w, const float* __restrict__ proj_w,
          const float* __restrict__ mlp_w1, const float* __restrict__ mlp_w2,
          bf16* qkvw_t, bf16* projw_t, bf16* mlpw1_t, bf16* mlpw2_t,
          const float* __restrict__ x, const float* __restrict__ ln1_w,
          const float* __restrict__ ln1_b, bf16* xnA) {
  __shared__ float t[32][33];
  __shared__ float sm[4], sv[4];
  int idx = blockIdx.x, tid = threadIdx.x;
  if (idx < 1728)       wt_conv_dev(qkv_w,  qkvw_t,  768,  2304, idx,        tid, t);
  else if (idx < 2304)  wt_conv_dev(proj_w, projw_t, 768,  768,  idx - 1728, tid, t);
  else if (idx < 4608)  wt_conv_dev(mlp_w1, mlpw1_t, 768,  3072, idx - 2304, tid, t);
  else if (idx < 6912)  wt_conv_dev(mlp_w2, mlpw2_t, 3072, 768,  idx - 4608, tid, t);
  else {
    int row = idx - 6912;  // 0..M_-1
    ln_dev(x + (size_t)row * D_, ln1_w, ln1_b, xnA + (size_t)row * D_, tid, sm, sv);
  }
}

// ---------------- bf16 GEMM, counted-vmcnt pipeline, DEPTH in {3,4} ----------------
// C = A(rows x KSTRIDE) * Bt(NxKSTRIDE)^T over K-chunk [kbase, kbase+KCHUNK).
// grid.x = (MPAD/BM)*(N/128) swizzled blocks; grid.y = K-chunk index (split-K).
// MODE 0: + bias -> scatter to QKV buffer [3][B][S][768] bf16
// MODE 2: + bias -> gelu(exact) -> bf16 dst [M_][N]  (rows < M_ only)
// MODE 3: bf16 partial -> dst + blockIdx.y*MPAD*N (no bias, all rows)
template<int BM, int DEPTH, int N, int KSTRIDE, int KCHUNK, int MODE>
__global__ __launch_bounds__(256)
void gemm_bf16(const bf16* __restrict__ A, const bf16* __restrict__ Bt,
               const float* __restrict__ bias, void* __restrict__ dst) {
  constexpr int MR   = BM / 32;        // m-fragments per wave (wave rows = MR*16)
  constexpr int LPS  = BM / 64 + 2;    // global_load_lds per thread per stage
  constexpr int TN   = N / 128;
  constexpr int NBLK = (MPAD / BM) * TN;
  __shared__ bf16 ldsA[DEPTH][BM * 32];
  __shared__ bf16 ldsB[DEPTH][128 * 32];

  // bijective XCD-chunked remap (m204): XCD k gets a contiguous tm-major chunk
  int bid = blockIdx.x;
  constexpr int NQ = NBLK >> 3, NR = NBLK & 7;
  int xcd = bid & 7, off = bid >> 3;
  int swz = (xcd < NR ? xcd * (NQ + 1) : NR * (NQ + 1) + (xcd - NR) * NQ) + off;
  const int tm = swz / TN, tn = swz % TN;
  const int kbase = blockIdx.y * KCHUNK;

  const int tid = threadIdx.x;
  const int wid = tid >> 6, lane = tid & 63;
  const int wr = wid >> 1, wc = wid & 1;

  auto stage = [&](int bufi, int step) {
    const int k0 = kbase + step * 32;
#pragma unroll
    for (int i = 0; i < BM / 64; ++i) {
      int c = wid * 64 + i * 256 + lane;
      int r = c >> 2, slot = c & 3;
      int gs = slot ^ ((r >> 1) & 3);  // inverse-swizzled global source (rule 21)
      const bf16* ga = A + (size_t)(tm * BM + r) * KSTRIDE + k0 + gs * 8;
      bf16* la = &ldsA[bufi][(wid * 64 + i * 256) * 8];
      __builtin_amdgcn_global_load_lds(
          (__attribute__((address_space(1))) void*)ga,
          (__attribute__((address_space(3))) void*)la, 16, 0, 0);
    }
#pragma unroll
    for (int i = 0; i < 2; ++i) {
      int c = wid * 64 + i * 256 + lane;
      int r = c >> 2, slot = c & 3;
      int gs = slot ^ ((r >> 1) & 3);
      const bf16* ga = Bt + (size_t)(tn * 128 + r) * KSTRIDE + k0 + gs * 8;
      bf16* la = &ldsB[bufi][(wid * 64 + i * 256) * 8];
      __builtin_amdgcn_global_load_lds(
          (__attribute__((address_space(1))) void*)ga,
          (__attribute__((address_space(3))) void*)la, 16, 0, 0);
    }
  };

  f4v acc[MR][4] = {};
  const int nk = KCHUNK / 32;

  stage(0, 0); stage(1, 1);
  if constexpr (DEPTH == 4) stage(2, 2);

#pragma unroll 4
  for (int kt = 0; kt < nk; ++kt) {
    const int rem = nk - kt;
    if constexpr (DEPTH == 4) {
      if (rem > 2) {             // 3 stages in flight; leave 2
        if constexpr (LPS == 4) WAITVM(8); else WAITVM(6);
      } else if (rem == 2) {
        if constexpr (LPS == 4) WAITVM(4); else WAITVM(3);
      } else WAITVM(0);
    } else {
      if (rem > 1) {             // 2 stages in flight; leave 1
        if constexpr (LPS == 4) WAITVM(4); else WAITVM(3);
      } else WAITVM(0);
    }
    __builtin_amdgcn_s_barrier();   // stage(kt) visible; oldest buffer free (WAR ok)
    MEMFENCE;
    if constexpr (DEPTH == 4) {
      if (kt + 3 < nk) stage((kt + 3) & 3, kt + 3);
    } else {
      if (kt + 2 < nk) stage((kt + 2) % 3, kt + 2);
    }

    const int cur = (DEPTH == 4) ? (kt & 3) : (kt % 3);
    s8v af[MR], bfv[4];
#pragma unroll
    for (int m = 0; m < MR; ++m) {
      int row = wr * (MR * 16) + m * 16 + (lane & 15);
      int slot = (lane >> 4) ^ ((row >> 1) & 3);
      af[m] = *(const s8v*)&ldsA[cur][row * 32 + slot * 8];
    }
#pragma unroll
    for (int n = 0; n < 4; ++n) {
      int row = wc * 64 + n * 16 + (lane & 15);
      int slot = (lane >> 4) ^ ((row >> 1) & 3);
      bfv[n] = *(const s8v*)&ldsB[cur][row * 32 + slot * 8];
    }
#pragma unroll
    for (int m = 0; m < MR; ++m)
#pragma unroll
      for (int n = 0; n < 4; ++n)
        acc[m][n] = __builtin_amdgcn_mfma_f32_16x16x32_bf16(af[m], bfv[n], acc[m][n], 0, 0, 0);
  }

#pragma unroll
  for (int m = 0; m < MR; ++m)
#pragma unroll
    for (int n = 0; n < 4; ++n)
#pragma unroll
      for (int j = 0; j < 4; ++j) {
        int row = tm * BM + wr * (MR * 16) + m * 16 + (lane >> 4) * 4 + j;
        int col = tn * 128 + wc * 64 + n * 16 + (lane & 15);   // C: col=l&15 (m89)
        float v = acc[m][n][j];
        if (MODE == 0) {
          if (row < M_) {
            float val = v + bias[col];
            int which = col / 768, rem2 = col % 768;
            int bb = row / S_, s = row % S_;
            ((bf16*)dst)[((size_t)(which * B_ + bb) * S_ + s) * 768 + rem2] =
                __float2bfloat16(val);
          }
        } else if (MODE == 2) {
          if (row < M_) {
            float val = v + bias[col];
            val = 0.5f * val * (1.f + erff(val * 0.70710678f));
            ((bf16*)dst)[(size_t)row * N + col] = __float2bfloat16(val);
          }
        } else {
          bf16* p = (bf16*)dst + (size_t)blockIdx.y * MPAD * N;
          p[(size_t)row * N + col] = __float2bfloat16(v);
        }
      }
}

// ---------------- proj reduce + residual + LN2, fused (one row per block) ----------------
__global__ __launch_bounds__(256)
void projfix(const bf16* __restrict__ part, const float* __restrict__ x,
             const float* __restrict__ pbias, const float* __restrict__ lnw,
             const float* __restrict__ lnb, float* __restrict__ out,
             bf16* __restrict__ h2) {
  int row = blockIdx.x, t = threadIdx.x;
  const bf16* p0 = part + (size_t)row * D_;
  const bf16* p1 = part + (size_t)MPAD * D_ + (size_t)row * D_;
  const float* xr = x + (size_t)row * D_;
  float v[3];
#pragma unroll
  for (int i = 0; i < 3; ++i) {
    int c = t + i * 256;
    v[i] = xr[c] + pbias[c] + __bfloat162float(p0[c]) + __bfloat162float(p1[c]);
  }
  float* orow = out + (size_t)row * D_;
#pragma unroll
  for (int i = 0; i < 3; ++i) orow[t + i * 256] = v[i];
  float s = v[0] + v[1] + v[2];
  float ss = v[0] * v[0] + v[1] * v[1] + v[2] * v[2];
#pragma unroll
  for (int o = 32; o; o >>= 1) { s += __shfl_xor(s, o); ss += __shfl_xor(ss, o); }
  __shared__ float sm[4], sv[4];
  if ((t & 63) == 0) { sm[t >> 6] = s; sv[t >> 6] = ss; }
  __syncthreads();
  float S = sm[0] + sm[1] + sm[2] + sm[3];
  float SS = sv[0] + sv[1] + sv[2] + sv[3];
  float mean = S * (1.f / D_);
  float var  = SS * (1.f / D_) - mean * mean;
  float inv  = rsqrtf(var + 1e-5f);
  bf16* hrow = h2 + (size_t)row * D_;
#pragma unroll
  for (int i = 0; i < 3; ++i) {
    int c = t + i * 256;
    hrow[c] = __float2bfloat16((v[i] - mean) * inv * lnw[c] + lnb[c]);
  }
}

// ---------------- mlp2 split-K reduce (in-place residual) ----------------
__global__ __launch_bounds__(256)
void reduceK(const bf16* __restrict__ part, const float* __restrict__ bias,
             float* __restrict__ out) {
  int i = blockIdx.x * 256 + threadIdx.x;   // float4 units; M_*768/4 total
  ushort4 a = ((const ushort4*)part)[i];
  ushort4 b = ((const ushort4*)(part + (size_t)MPAD * 768))[i];
  float4 s = ((const float4*)out)[i];
  int col = (i * 4) % D_;
  float4 bv = *(const float4*)&bias[col];
  float4 o;
  o.x = s.x + bv.x + __bfloat162float(__hip_bfloat16_raw{a.x}) + __bfloat162float(__hip_bfloat16_raw{b.x});
  o.y = s.y + bv.y + __bfloat162float(__hip_bfloat16_raw{a.y}) + __bfloat162float(__hip_bfloat16_raw{b.y});
  o.z = s.z + bv.z + __bfloat162float(__hip_bfloat16_raw{a.z}) + __bfloat162float(__hip_bfloat16_raw{b.z});
  o.w = s.w + bv.w + __bfloat162float(__hip_bfloat16_raw{a.w}) + __bfloat162float(__hip_bfloat16_raw{b.w});
  ((float4*)out)[i] = o;
}

// ---------------- attention: cls FIRST (blocks 0..47), routed after ----------------
__global__ __launch_bounds__(256)
void attn_kernel(const bf16* __restrict__ QKV, const int* __restrict__ routes,
                 bf16* __restrict__ out) {
  __shared__ float qf[64];
  __shared__ float sc[S_];
  __shared__ float red[4];
  __shared__ float pv[4][64];

  if (blockIdx.x >= 48) {
    // ---- routed: one wave per (b,p,h); all Q/K/V loads issued before softmax ----
    int unit = (blockIdx.x - 48) * 4 + (threadIdx.x >> 6);  // (b*P + p)*H + h
    int lane = threadIdx.x & 63;
    int h = unit % H_;
    int bp = unit / H_;
    int p = bp % P_, b = bp / P_;

    int k = lane & 31, hi = lane >> 5;
    int r = routes[p * KNB + k] + 1;

    const bf16* Qp = QKV + ((size_t)(0 * B_ + b) * S_ + (p + 1)) * D_ + h * 64 + hi * 32;
    const bf16* Kb = QKV + ((size_t)(1 * B_ + b) * S_) * D_;
    const bf16* Vb = QKV + ((size_t)(2 * B_ + b) * S_) * D_;

    // issue ALL loads up front: Q(4), K(4), V(4) x 16B per lane
    const uint4* q4 = (const uint4*)Qp;
    const uint4* k4 = (const uint4*)(Kb + (size_t)r * D_ + h * 64 + hi * 32);
    int c = lane & 7, kr0 = lane >> 3;
    uint4 qv[4], kv[4], vv[4];
#pragma unroll
    for (int i = 0; i < 4; ++i) { qv[i] = q4[i]; kv[i] = k4[i]; }
#pragma unroll
    for (int j = 0; j < 4; ++j) {
      int kj = kr0 + 8 * j;              // 0..31
      int rj = __shfl(r, kj);
      vv[j] = *(const uint4*)(Vb + (size_t)rj * D_ + h * 64 + c * 8);
    }

    float dot = 0.f;
#pragma unroll
    for (int i = 0; i < 4; ++i) {
      dot += b2f_lo(kv[i].x) * b2f_lo(qv[i].x) + b2f_hi(kv[i].x) * b2f_hi(qv[i].x)
           + b2f_lo(kv[i].y) * b2f_lo(qv[i].y) + b2f_hi(kv[i].y) * b2f_hi(qv[i].y)
           + b2f_lo(kv[i].z) * b2f_lo(qv[i].z) + b2f_hi(kv[i].z) * b2f_hi(qv[i].z)
           + b2f_lo(kv[i].w) * b2f_lo(qv[i].w) + b2f_hi(kv[i].w) * b2f_hi(qv[i].w);
    }
    dot += __shfl_xor(dot, 32);
    float scv = dot * 0.125f;

    float mx = scv;
#pragma unroll
    for (int o = 16; o; o >>= 1) mx = fmaxf(mx, __shfl_xor(mx, o));
    float w = __expf(scv - mx);
    float sum = w;
#pragma unroll
    for (int o = 16; o; o >>= 1) sum += __shfl_xor(sum, o);
    float inv = 1.f / sum;

    float acc[8] = {};
#pragma unroll
    for (int j = 0; j < 4; ++j) {
      int kj = kr0 + 8 * j;
      float wj = __shfl(w, kj);
      acc[0] += wj * b2f_lo(vv[j].x); acc[1] += wj * b2f_hi(vv[j].x);
      acc[2] += wj * b2f_lo(vv[j].y); acc[3] += wj * b2f_hi(vv[j].y);
      acc[4] += wj * b2f_lo(vv[j].z); acc[5] += wj * b2f_hi(vv[j].z);
      acc[6] += wj * b2f_lo(vv[j].w); acc[7] += wj * b2f_hi(vv[j].w);
    }
#pragma unroll
    for (int s = 8; s < 64; s <<= 1)
#pragma unroll
      for (int d = 0; d < 8; ++d) acc[d] += __shfl_xor(acc[d], s);

    if (lane < 8) {
      s8v o;
#pragma unroll
      for (int d = 0; d < 8; ++d) o[d] = (short)f2bu(acc[d] * inv);
      *(s8v*)(out + ((size_t)(b * S_ + p + 1)) * D_ + h * 64 + c * 8) = o;
    }
  } else {
    // ---- cls token: one block per (b,h), full-S softmax; runs under routed shadow ----
    int bh = blockIdx.x;
    int b = bh / H_, h = bh % H_;
    const bf16* q  = QKV + ((size_t)(0 * B_ + b) * S_) * D_ + h * 64;
    const bf16* Kr = QKV + ((size_t)(1 * B_ + b) * S_) * D_ + h * 64;
    const bf16* Vr = QKV + ((size_t)(2 * B_ + b) * S_) * D_ + h * 64;
    int t = threadIdx.x;
    if (t < 64) qf[t] = __bfloat162float(q[t]);
    __syncthreads();
    for (int kk = t; kk < S_; kk += 256) {
      const uint4* k4 = (const uint4*)(Kr + (size_t)kk * D_);
      float s = 0.f;
#pragma unroll
      for (int i = 0; i < 8; ++i) {
        uint4 kv = k4[i];
        const float* q8 = &qf[i * 8];
        s += b2f_lo(kv.x) * q8[0] + b2f_hi(kv.x) * q8[1]
           + b2f_lo(kv.y) * q8[2] + b2f_hi(kv.y) * q8[3]
           + b2f_lo(kv.z) * q8[4] + b2f_hi(kv.z) * q8[5]
           + b2f_lo(kv.w) * q8[6] + b2f_hi(kv.w) * q8[7];
      }
      sc[kk] = s * 0.125f;
    }
    __syncthreads();
    float mx = -1e30f;
    for (int kk = t; kk < S_; kk += 256) mx = fmaxf(mx, sc[kk]);
#pragma unroll
    for (int o = 32; o; o >>= 1) mx = fmaxf(mx, __shfl_xor(mx, o));
    if ((t & 63) == 0) red[t >> 6] = mx;
    __syncthreads();
    float M = fmaxf(fmaxf(red[0], red[1]), fmaxf(red[2], red[3]));
    __syncthreads();
    float sum = 0.f;
    for (int kk = t; kk < S_; kk += 256) { float e = __expf(sc[kk] - M); sc[kk] = e; sum += e; }
#pragma unroll
    for (int o = 32; o; o >>= 1) sum += __shfl_xor(sum, o);
    if ((t & 63) == 0) red[t >> 6] = sum;
    __syncthreads();
    float L = red[0] + red[1] + red[2] + red[3];
    float inv = 1.f / L;
    int d = t & 63, kg = t >> 6;
    float acc = 0.f;
    for (int kk = kg; kk < S_; kk += 4)
      acc += sc[kk] * __bfloat162float(Vr[(size_t)kk * D_ + d]);
    pv[kg][d] = acc;
    __syncthreads();
    if (t < 64) {
      float ov = (pv[0][t] + pv[1][t] + pv[2][t] + pv[3][t]) * inv;
      out[(size_t)(b * S_) * D_ + h * 64 + t] = __float2bfloat16(ov);
    }
  }
}

extern "C" void kernel_launch(void* const* d_in, const int* in_sizes, int n_in,
                              void* d_out, int out_size, void* d_ws, size_t ws_size,
                              hipStream_t stream) {
  const float* x      = (const float*)d_in[0];
  const int*   routes = (const int*)d_in[1];
  const float* qkv_w  = (const float*)d_in[2];
  const float* qkv_b  = (const float*)d_in[3];
  const float* proj_w = (const float*)d_in[4];
  const float* proj_b = (const float*)d_in[5];
  const float* ln1_w  = (const float*)d_in[6];
  const float* ln1_b  = (const float*)d_in[7];
  const float* ln2_w  = (const float*)d_in[8];
  const float* ln2_b  = (const float*)d_in[9];
  const float* mlp_w1 = (const float*)d_in[10];
  const float* mlp_b1 = (const float*)d_in[11];
  const float* mlp_w2 = (const float*)d_in[12];
  const float* mlp_b2 = (const float*)d_in[13];
  float* out = (float*)d_out;

  // workspace layout (~52.5 MB, same footprint as proven rounds)
  bf16* qkvw_t  = (bf16*)d_ws;                       // [2304][768]
  bf16* projw_t = qkvw_t + 2304 * 768;               // [768][768]
  bf16* mlpw1_t = projw_t + 768 * 768;               // [3072][768]
  bf16* mlpw2_t = mlpw1_t + 3072 * 768;              // [768][3072]
  bf16* xnA     = mlpw2_t + 768 * 3072;              // [4224][768]
  bf16* qkvbuf  = xnA + (size_t)MPAD * 768;          // [3][B][S][768] s-major
  bf16* attn    = qkvbuf + (size_t)3 * B_ * S_ * 768;  // [4224][768]
  bf16* h2      = attn + (size_t)MPAD * 768;         // [4224][768]
  // aliases (lifetime-checked, all proven in R5/R6 passes):
  bf16* g       = xnA;   // [M_][3072]: fits xnA+qkvbuf; pad-row reads harmless
  bf16* projp   = xnA;   // proj partials [2][MPAD][768] over xnA+qkvbuf-head (dead)
  bf16* mlp2p   = attn;  // mlp2 partials [2][MPAD][768] over attn+h2 (dead by then)

  // 1. prep: all 4 weight converts + LN1
  prep<<<6912 + M_, 256, 0, stream>>>(qkv_w, proj_w, mlp_w1, mlp_w2,
                                      qkvw_t, projw_t, mlpw1_t, mlpw2_t,
                                      x, ln1_w, ln1_b, xnA);

  // 2. qkv GEMM (BM=128, depth-4) -> scatter [3][B][S][768]
  gemm_bf16<128, 4, 2304, 768, 768, 0><<<33 * 18, 256, 0, stream>>>(xnA, qkvw_t, qkv_b, qkvbuf);

  // 3. attention: cls blocks first, routed after (no tail, no combine)
  attn_kernel<<<48 + 12288, 256, 0, stream>>>(qkvbuf, routes, attn);

  // 4. proj split-K x2 partials (BM=64, depth-3)
  gemm_bf16<64, 3, 768, 768, 384, 3><<<dim3(66 * 6, 2), 256, 0, stream>>>(attn, projw_t, nullptr, projp);

  // 5. fused: out = x + proj_b + p0 + p1 ; h2 = LN2(out)
  projfix<<<M_, 256, 0, stream>>>(projp, x, proj_b, ln2_w, ln2_b, out, h2);

  // 6. mlp1 + GELU (BM=128, depth-4)
  gemm_bf16<128, 4, 3072, 768, 768, 2><<<33 * 24, 256, 0, stream>>>(h2, mlpw1_t, mlp_b1, g);

  // 7. mlp2 split-K x2 partials (BM=64, depth-3)
  gemm_bf16<64, 3, 768, 3072, 1536, 3><<<dim3(66 * 6, 2), 256, 0, stream>>>(g, mlpw2_t, nullptr, mlp2p);

  // 8. final reduce: out += mlp_b2 + p0 + p1
  reduceK<<<(M_ * D_) / 1024, 256, 0, stream>>>(mlp2p, mlp_b2, out);
}